// Round 10
// baseline (187.066 us; speedup 1.0000x reference)
//
#include <hip/hip_runtime.h>
#include <cstddef>
#include <cstdint>

// DigitCaps dynamic routing — round 10: i-split across 2 blocks/CU, with the
// round-9 spill fixed.
// Round-9 post-mortem: __launch_bounds__(1024,8) made the compiler squeeze to
// 32 VGPR and spill the ~60-reg routing live set (41 MB scratch writes/sweep,
// 78 us each). Occupancy DID hit ~72% -> the 2-blocks/CU structure works.
// Fix: (a) plain __launch_bounds__(1024) — natural ~60 VGPR rounds to 64
// alloc = exactly 8 waves/SIMD x 64 = 512-reg pool, 2 blocks still fit;
// (b) fully-packed softmax tail (e stored as f16 pairs in ppk, packed es and
// coefficient mul) removes the 20 live f32 e0/e1 temps.
//   wprep -> sweep<0> -> combine<0> -> sweep<1> -> combine<1> -> sweep<2> -> combine<2>
// B=512, O=10, I=1152, OW=16, S=8, ITER=3.

typedef _Float16 h2 __attribute__((ext_vector_type(2)));
typedef __fp16 fp16v2 __attribute__((ext_vector_type(2)));  // cvt_pkrtz ret type

constexpr int O_ = 10, I_ = 1152, W_ = 16, S_ = 8;
constexpr int BQ = 2;               // batch items per block
constexpr int NTH = 1024, NWV = 16;
constexpr int IH = I_ / 2;          // 576: i per block (half range)
constexpr int SLOTS = NWV * 4;      // 64 concurrent i (16 lanes per i)
constexpr int KSEQ = IH / SLOTS;    // 9 sequential i per lane per sweep
constexpr int WROW = O_ * W_ * S_;  // 1280 halves per i in transposed W
constexpr int NBP = 256;            // batch pairs
constexpr int OW = O_ * W_;         // 160

union U32H2 { uint32_t u; h2 h; fp16v2 f; };
__device__ __forceinline__ h2 as_h2(uint32_t u) { U32H2 c; c.u = u; return c.h; }
__device__ __forceinline__ uint32_t as_u32(h2 h) { U32H2 c; c.h = h; return c.u; }
__device__ __forceinline__ h2 cvt_pk(float a, float b) {
  U32H2 c; c.f = __builtin_amdgcn_cvt_pkrtz(a, b); return c.h;
}

// W prep: fp32 [o][i][w][s] -> f16 [i][o][w][s]  (2,949,120 B into d_ws)
constexpr int W4TOT = O_ * I_ * W_ * S_ / 4;  // 368640 float4s
__global__ __launch_bounds__(256) void wprep(const float4* __restrict__ Wg,
                                             uint2* __restrict__ Wt) {
  int idx = blockIdx.x * 256 + threadIdx.x;
  if (idx >= W4TOT) return;
  int w2 = idx & 31;
  int oi = idx >> 5;        // o*I_ + i
  int o = oi / I_;
  int i = oi - o * I_;
  float4 v = Wg[idx];
  uint2 pk;
  pk.x = as_u32(cvt_pk(v.x, v.y));
  pk.y = as_u32(cvt_pk(v.z, v.w));
  Wt[(i * O_ + o) * 32 + w2] = pk;
}

__device__ __forceinline__ float dot8(const uint4& wv, const uint32_t* xr) {
  return __builtin_amdgcn_fdot2(as_h2(wv.x), as_h2(xr[0]),
          __builtin_amdgcn_fdot2(as_h2(wv.y), as_h2(xr[1]),
           __builtin_amdgcn_fdot2(as_h2(wv.z), as_h2(xr[2]),
            __builtin_amdgcn_fdot2(as_h2(wv.w), as_h2(xr[3]),
                                   0.f, false), false), false), false);
}

// Sweep: 512 blocks; block = (batch-pair bp, i-half h). Computes the partial
// s over its 576 i's and writes P[(bp*2+h)][bb][r]. PASS>0 reads Vcur.
template <int PASS>
__global__ __launch_bounds__(NTH) void sweep(
    const float* __restrict__ xg, const _Float16* __restrict__ Wt,
    const float* __restrict__ Vcur, float* __restrict__ P) {
  __shared__ _Float16 xl[BQ * IH * S_];      // 18,432 B
  __shared__ float s_buf[NWV][BQ][O_][W_];   // 20,480 B

  const int tid = threadIdx.x, blk = blockIdx.x;
  const int bp = blk >> 1, h = blk & 1, b0 = bp * BQ;
  const int wave = tid >> 6, lane = tid & 63;
  const int wg = lane & 15;     // w column 0..15
  const int isub = lane >> 4;   // 0..3
  const int ib = wave * 4 + isub;  // local i-slot; il = ib + 64*k

  // ---- stage this block's x slice -> f16 LDS ----
  {
    const float4* xb = (const float4*)xg;
    uint2* xw = (uint2*)xl;
#pragma unroll
    for (int j = 0; j < 3; ++j) {
      int f = j * NTH + tid;                 // 2304 float4s total
      if (f < BQ * IH * S_ / 4) {
        int b = f / (IH * S_ / 4);           // 0..1
        int rem = f - b * (IH * S_ / 4);
        float4 v = xb[(size_t)(b0 + b) * (I_ * S_ / 4) + h * (IH * S_ / 4) + rem];
        uint2 pk;
        pk.x = as_u32(cvt_pk(v.x, v.y));
        pk.y = as_u32(cvt_pk(v.z, v.w));
        xw[f] = pk;
      }
    }
  }
  __syncthreads();

  if (PASS == 0) {
    float S[BQ][O_];
#pragma unroll
    for (int b = 0; b < BQ; ++b)
#pragma unroll
      for (int o = 0; o < O_; ++o) S[b][o] = 0.f;

#pragma unroll 2
    for (int k = 0; k < KSEQ; ++k) {
      const int il = ib + SLOTS * k;
      const int gi = h * IH + il;
      uint32_t xr[BQ][4];
#pragma unroll
      for (int b = 0; b < BQ; ++b) {
        uint4 t = *(const uint4*)&xl[(b * IH + il) * S_];
        xr[b][0] = t.x; xr[b][1] = t.y; xr[b][2] = t.z; xr[b][3] = t.w;
      }
      const _Float16* wi = Wt + (size_t)gi * WROW + wg * S_;
#pragma unroll
      for (int o = 0; o < O_; ++o) {
        uint4 wv = *(const uint4*)(wi + o * (W_ * S_));
#pragma unroll
        for (int b = 0; b < BQ; ++b) S[b][o] += dot8(wv, xr[b]);
      }
    }
#pragma unroll
    for (int b = 0; b < BQ; ++b)
#pragma unroll
      for (int o = 0; o < O_; ++o) {
        float s = S[b][o];
        s += __shfl_xor(s, 16);
        s += __shfl_xor(s, 32);
        S[b][o] = s;
      }
    if (isub == 0) {
#pragma unroll
      for (int b = 0; b < BQ; ++b)
#pragma unroll
        for (int o = 0; o < O_; ++o) s_buf[wave][b][o][wg] = S[b][o];
    }
  } else {
    // packed batch-pair routing; fully-packed softmax tail
    h2 vrpk[O_];
#pragma unroll
    for (int o = 0; o < O_; ++o)
      vrpk[o] = cvt_pk(Vcur[(size_t)(b0 + 0) * OW + o * W_ + wg],
                       Vcur[(size_t)(b0 + 1) * OW + o * W_ + wg]);
    h2 Spk[O_];
#pragma unroll
    for (int o = 0; o < O_; ++o) Spk[o] = h2{(_Float16)0, (_Float16)0};

#pragma unroll 2
    for (int k = 0; k < KSEQ; ++k) {
      const int il = ib + SLOTS * k;
      const int gi = h * IH + il;
      uint32_t xr[BQ][4];
#pragma unroll
      for (int b = 0; b < BQ; ++b) {
        uint4 t = *(const uint4*)&xl[(b * IH + il) * S_];
        xr[b][0] = t.x; xr[b][1] = t.y; xr[b][2] = t.z; xr[b][3] = t.w;
      }
      const _Float16* wi = Wt + (size_t)gi * WROW + wg * S_;
      h2 upk[O_], ppk[O_];
#pragma unroll
      for (int o = 0; o < O_; ++o) {
        uint4 wv = *(const uint4*)(wi + o * (W_ * S_));
        float u0 = dot8(wv, xr[0]);
        float u1 = dot8(wv, xr[1]);
        upk[o] = cvt_pk(u0, u1);
        ppk[o] = upk[o] * vrpk[o];
      }
#pragma unroll
      for (int o = 0; o < O_; ++o) {
#pragma unroll
        for (int d = 1; d <= 8; d <<= 1)
          ppk[o] = ppk[o] + as_h2((uint32_t)__shfl_xor((int)as_u32(ppk[o]), d));
      }
      // softmax over o — packed end-to-end: e back into ppk (f16 pairs),
      // packed es accumulate, one packed coefficient multiply.
      h2 es_pk = h2{(_Float16)0, (_Float16)0};
#pragma unroll
      for (int o = 0; o < O_; ++o) {
        h2 e = cvt_pk(__expf((float)ppk[o][0]), __expf((float)ppk[o][1]));
        ppk[o] = e;
        es_pk = es_pk + e;
      }
      const h2 inv_pk = cvt_pk(1.0f / (float)es_pk[0], 1.0f / (float)es_pk[1]);
#pragma unroll
      for (int o = 0; o < O_; ++o)
        Spk[o] = Spk[o] + (ppk[o] * inv_pk) * upk[o];
    }
#pragma unroll
    for (int o = 0; o < O_; ++o) {
      Spk[o] = Spk[o] + as_h2((uint32_t)__shfl_xor((int)as_u32(Spk[o]), 16));
      Spk[o] = Spk[o] + as_h2((uint32_t)__shfl_xor((int)as_u32(Spk[o]), 32));
    }
    if (isub == 0) {
#pragma unroll
      for (int o = 0; o < O_; ++o) {
        s_buf[wave][0][o][wg] = (float)Spk[o][0];
        s_buf[wave][1][o][wg] = (float)Spk[o][1];
      }
    }
  }
  __syncthreads();

  // block partial (sum over 16 waves) -> global P
  if (tid < BQ * OW) {
    const int bb = tid / OW;
    const int r = tid % OW;
    float s = 0.f;
#pragma unroll
    for (int wv = 0; wv < NWV; ++wv) s += s_buf[wv][bb][r >> 4][r & 15];
    P[((size_t)(bp * 2 + h) * BQ + bb) * OW + r] = s;
  }
}

// Combine: 256 blocks x 320 threads. Sum the two i-half partials, squash,
// update Vcur / V1 / out.
template <int PASS>
__global__ __launch_bounds__(320) void combine(
    const float* __restrict__ P, float* __restrict__ Vcur,
    float* __restrict__ V1, float* __restrict__ out) {
  const int bp = blockIdx.x, tid = threadIdx.x;   // tid < 320
  const int bb = tid / OW, r = tid % OW;
  float s = P[((size_t)(bp * 2 + 0) * BQ + bb) * OW + r]
          + P[((size_t)(bp * 2 + 1) * BQ + bb) * OW + r];
  if (PASS == 0) s *= 0.1f;
  float n2 = s * s;
  n2 += __shfl_xor(n2, 1);
  n2 += __shfl_xor(n2, 2);
  n2 += __shfl_xor(n2, 4);
  n2 += __shfl_xor(n2, 8);
  const float v = s * sqrtf(n2) / (1.0f + n2);  // == (n2/(1+n2))*s/sqrt(n2)
  const size_t gi = (size_t)(bp * BQ + bb) * OW + r;
  if (PASS == 0)      { Vcur[gi] = v; V1[gi] = v; }
  else if (PASS == 1) { Vcur[gi] = V1[gi] + v; }   // v1+v2 for pass 2
  else                { out[gi] = v; }
}

extern "C" void kernel_launch(void* const* d_in, const int* in_sizes, int n_in,
                              void* d_out, int out_size, void* d_ws, size_t ws_size,
                              hipStream_t stream) {
  const float* x = (const float*)d_in[0];   // [512, 1152, 8]
  const float* W = (const float*)d_in[1];   // [1, 10, 1152, 16, 8]
  float* out = (float*)d_out;               // [512, 10, 16]

  // ws layout: Wt (2,949,120 B) | P (655,360 B) | Vcur (327,680 B) | V1 (327,680 B)
  _Float16* Wt = (_Float16*)d_ws;
  float* P  = (float*)((char*)d_ws + 2949120);
  float* Vc = (float*)((char*)d_ws + 2949120 + 655360);
  float* V1 = (float*)((char*)d_ws + 2949120 + 655360 + 327680);

  hipLaunchKernelGGL(wprep, dim3((W4TOT + 255) / 256), dim3(256), 0, stream,
                     (const float4*)W, (uint2*)Wt);
  sweep<0><<<dim3(2 * NBP), dim3(NTH), 0, stream>>>(x, Wt, Vc, P);
  combine<0><<<dim3(NBP), dim3(320), 0, stream>>>(P, Vc, V1, out);
  sweep<1><<<dim3(2 * NBP), dim3(NTH), 0, stream>>>(x, Wt, Vc, P);
  combine<1><<<dim3(NBP), dim3(320), 0, stream>>>(P, Vc, V1, out);
  sweep<2><<<dim3(2 * NBP), dim3(NTH), 0, stream>>>(x, Wt, Vc, P);
  combine<2><<<dim3(NBP), dim3(320), 0, stream>>>(P, Vc, V1, out);
}

// Round 11
// 187.011 us; speedup vs baseline: 1.0003x; 1.0003x over previous
//
#include <hip/hip_runtime.h>
#include <cstddef>
#include <cstdint>

// DigitCaps dynamic routing — round 11: single fused kernel, 2 blocks/CU.
// r9/r10 isolated: __launch_bounds__(1024,8) => co-residency (occ 72%) but
// old f32 tail scratched at the 64-VGPR budget; r10's packed tail needs only
// 36 VGPR. Combine: fused kernel (x staged once, no launch overhead) +
// grid=512/BQ=1 + (1024,8) + o-pair packed routing tail.
// B=512, O=10, I=1152, OW=16, S=8, ITER=3.
//   pass0: s1 = 0.1*sum_i u ; v1
//   pass1: b = u.v1      -> softmax -> s2 ; v2
//   pass2: b = u.(v1+v2) -> softmax -> s3 ; out
// u recomputed per pass from f16 W (transposed [i][o][w][s] in d_ws, 2.95 MB,
// L2-resident) and f16 x (staged once in LDS).

typedef _Float16 h2 __attribute__((ext_vector_type(2)));
typedef __fp16 fp16v2 __attribute__((ext_vector_type(2)));  // cvt_pkrtz ret type

constexpr int O_ = 10, I_ = 1152, W_ = 16, S_ = 8;
constexpr int NTH = 1024, NWV = 16;
constexpr int SLOTS = NWV * 4;      // 64 concurrent i (16 lanes per i)
constexpr int KSEQ = I_ / SLOTS;    // 18 sequential i per lane per pass
constexpr int OQ = O_ / 2;          // 5 packed o-pairs
constexpr int WROW = O_ * W_ * S_;  // 1280 halves per i in transposed W
constexpr int OW = O_ * W_;         // 160

union U32H2 { uint32_t u; h2 h; fp16v2 f; };
__device__ __forceinline__ h2 as_h2(uint32_t u) { U32H2 c; c.u = u; return c.h; }
__device__ __forceinline__ uint32_t as_u32(h2 h) { U32H2 c; c.h = h; return c.u; }
__device__ __forceinline__ h2 cvt_pk(float a, float b) {
  U32H2 c; c.f = __builtin_amdgcn_cvt_pkrtz(a, b); return c.h;
}

// W prep: fp32 [o][i][w][s] -> f16 [i][o][w][s]  (2,949,120 B into d_ws)
constexpr int W4TOT = O_ * I_ * W_ * S_ / 4;  // 368640 float4s
__global__ __launch_bounds__(256) void wprep(const float4* __restrict__ Wg,
                                             uint2* __restrict__ Wt) {
  int idx = blockIdx.x * 256 + threadIdx.x;
  if (idx >= W4TOT) return;
  int w2 = idx & 31;
  int oi = idx >> 5;        // o*I_ + i
  int o = oi / I_;
  int i = oi - o * I_;
  float4 v = Wg[idx];
  uint2 pk;
  pk.x = as_u32(cvt_pk(v.x, v.y));
  pk.y = as_u32(cvt_pk(v.z, v.w));
  Wt[(i * O_ + o) * 32 + w2] = pk;
}

__device__ __forceinline__ float dot8(const uint4& wv, const uint32_t* xr) {
  return __builtin_amdgcn_fdot2(as_h2(wv.x), as_h2(xr[0]),
          __builtin_amdgcn_fdot2(as_h2(wv.y), as_h2(xr[1]),
           __builtin_amdgcn_fdot2(as_h2(wv.z), as_h2(xr[2]),
            __builtin_amdgcn_fdot2(as_h2(wv.w), as_h2(xr[3]),
                                   0.f, false), false), false), false);
}

// 512 blocks (1 batch item each) x 1024 threads; min 8 waves/EU => 2 blocks/CU.
__global__ __launch_bounds__(NTH, 8) void digitcaps_fused(
    const float* __restrict__ xg, const _Float16* __restrict__ Wt,
    float* __restrict__ out) {
  __shared__ _Float16 xl[I_ * S_];        // 18,432 B (f16 x, one batch item)
  __shared__ float s_buf[NWV][O_][W_];    // 10,240 B
  __shared__ float vcur[OW];              // v1, then v1+v2
  __shared__ float v1s[OW];

  const int tid = threadIdx.x, blk = blockIdx.x;
  const int wave = tid >> 6, lane = tid & 63;
  const int wg = lane & 15;     // w column 0..15
  const int isub = lane >> 4;   // 0..3
  const int ib = wave * 4 + isub;  // i-slot; i = ib + 64*k

  // ---- stage x -> f16 LDS (once; reused by all 3 passes) ----
  {
    const float4* xb = (const float4*)(xg + (size_t)blk * (I_ * S_));
    uint2* xw = (uint2*)xl;
#pragma unroll
    for (int j = 0; j < 3; ++j) {
      int f = j * NTH + tid;            // 2304 float4s total
      if (f < I_ * S_ / 4) {
        float4 v = xb[f];
        uint2 pk;
        pk.x = as_u32(cvt_pk(v.x, v.y));
        pk.y = as_u32(cvt_pk(v.z, v.w));
        xw[f] = pk;
      }
    }
  }
  __syncthreads();

  // ================= pass 0 : c = 1/10 uniform (f32 accumulate) ============
  {
    float S0[O_];
#pragma unroll
    for (int o = 0; o < O_; ++o) S0[o] = 0.f;

#pragma unroll 2
    for (int k = 0; k < KSEQ; ++k) {
      const int i = ib + SLOTS * k;
      uint32_t xr[4];
      {
        uint4 t = *(const uint4*)&xl[i * S_];
        xr[0] = t.x; xr[1] = t.y; xr[2] = t.z; xr[3] = t.w;
      }
      const _Float16* wi = Wt + (size_t)i * WROW + wg * S_;
#pragma unroll
      for (int o = 0; o < O_; ++o) {
        uint4 wv = *(const uint4*)(wi + o * (W_ * S_));
        S0[o] += dot8(wv, xr);
      }
    }
#pragma unroll
    for (int o = 0; o < O_; ++o) {
      float s = S0[o];
      s += __shfl_xor(s, 16);
      s += __shfl_xor(s, 32);
      S0[o] = s;
    }
    if (isub == 0) {
#pragma unroll
      for (int o = 0; o < O_; ++o) s_buf[wave][o][wg] = S0[o];
    }
    __syncthreads();

    if (tid < OW) {
      const int r = tid;
      float s = 0.f;
#pragma unroll
      for (int wv = 0; wv < NWV; ++wv) s += s_buf[wv][r >> 4][r & 15];
      s *= 0.1f;
      float n2 = s * s;
      n2 += __shfl_xor(n2, 1);
      n2 += __shfl_xor(n2, 2);
      n2 += __shfl_xor(n2, 4);
      n2 += __shfl_xor(n2, 8);
      const float v = s * sqrtf(n2) / (1.0f + n2);
      vcur[r] = v;
      v1s[r] = v;
    }
    __syncthreads();
  }

  // ============== passes 1,2 : o-pair packed routing =======================
  for (int pass = 1; pass < 3; ++pass) {
    h2 vrpk[OQ];   // packed o-pair v slice for this lane's w column
#pragma unroll
    for (int oq = 0; oq < OQ; ++oq)
      vrpk[oq] = cvt_pk(vcur[(2 * oq) * W_ + wg], vcur[(2 * oq + 1) * W_ + wg]);

    h2 Spk[OQ];
#pragma unroll
    for (int oq = 0; oq < OQ; ++oq) Spk[oq] = h2{(_Float16)0, (_Float16)0};

#pragma unroll 2
    for (int k = 0; k < KSEQ; ++k) {
      const int i = ib + SLOTS * k;
      uint32_t xr[4];
      {
        uint4 t = *(const uint4*)&xl[i * S_];
        xr[0] = t.x; xr[1] = t.y; xr[2] = t.z; xr[3] = t.w;
      }
      const _Float16* wi = Wt + (size_t)i * WROW + wg * S_;
      h2 upk[OQ], ppk[OQ];
#pragma unroll
      for (int oq = 0; oq < OQ; ++oq) {
        uint4 wv0 = *(const uint4*)(wi + (2 * oq) * (W_ * S_));
        uint4 wv1 = *(const uint4*)(wi + (2 * oq + 1) * (W_ * S_));
        upk[oq] = cvt_pk(dot8(wv0, xr), dot8(wv1, xr));
        ppk[oq] = upk[oq] * vrpk[oq];       // v_pk_mul_f16
      }
      // logit reduce over the 16 w lanes (bits 0..3): packed o-pairs
#pragma unroll
      for (int oq = 0; oq < OQ; ++oq) {
#pragma unroll
        for (int d = 1; d <= 8; d <<= 1)
          ppk[oq] = ppk[oq] + as_h2((uint32_t)__shfl_xor((int)as_u32(ppk[oq]), d));
      }
      // softmax over o — packed: e back into ppk, cross-half sum for es
      h2 es_pk = h2{(_Float16)0, (_Float16)0};
#pragma unroll
      for (int oq = 0; oq < OQ; ++oq) {
        h2 e = cvt_pk(__expf((float)ppk[oq][0]), __expf((float)ppk[oq][1]));
        ppk[oq] = e;
        es_pk = es_pk + e;
      }
      const float inv = 1.0f / ((float)es_pk[0] + (float)es_pk[1]);
      const h2 inv_pk = cvt_pk(inv, inv);
#pragma unroll
      for (int oq = 0; oq < OQ; ++oq)
        Spk[oq] = Spk[oq] + (ppk[oq] * inv_pk) * upk[oq];
    }

    // reduce s over the 4 i-sub lane groups (bits 4,5)
#pragma unroll
    for (int oq = 0; oq < OQ; ++oq) {
      Spk[oq] = Spk[oq] + as_h2((uint32_t)__shfl_xor((int)as_u32(Spk[oq]), 16));
      Spk[oq] = Spk[oq] + as_h2((uint32_t)__shfl_xor((int)as_u32(Spk[oq]), 32));
    }
    if (isub == 0) {
#pragma unroll
      for (int oq = 0; oq < OQ; ++oq) {
        s_buf[wave][2 * oq][wg]     = (float)Spk[oq][0];
        s_buf[wave][2 * oq + 1][wg] = (float)Spk[oq][1];
      }
    }
    __syncthreads();

    // cross-wave reduce + squash on 160 threads
    if (tid < OW) {
      const int r = tid;
      float s = 0.f;
#pragma unroll
      for (int wv = 0; wv < NWV; ++wv) s += s_buf[wv][r >> 4][r & 15];
      float n2 = s * s;
      n2 += __shfl_xor(n2, 1);
      n2 += __shfl_xor(n2, 2);
      n2 += __shfl_xor(n2, 4);
      n2 += __shfl_xor(n2, 8);
      const float v = s * sqrtf(n2) / (1.0f + n2);  // == (n2/(1+n2))*s/sqrt(n2)
      if (pass == 1)  vcur[r] = v1s[r] + v;   // v1+v2 for pass 2
      else            out[(size_t)blk * OW + r] = v;
    }
    __syncthreads();
  }
}

extern "C" void kernel_launch(void* const* d_in, const int* in_sizes, int n_in,
                              void* d_out, int out_size, void* d_ws, size_t ws_size,
                              hipStream_t stream) {
  const float* x = (const float*)d_in[0];   // [512, 1152, 8]
  const float* W = (const float*)d_in[1];   // [1, 10, 1152, 16, 8]
  float* out = (float*)d_out;               // [512, 10, 16]
  _Float16* Wt = (_Float16*)d_ws;           // 2,949,120 B f16 transposed W

  hipLaunchKernelGGL(wprep, dim3((W4TOT + 255) / 256), dim3(256), 0, stream,
                     (const float4*)W, (uint2*)Wt);
  hipLaunchKernelGGL(digitcaps_fused, dim3(512), dim3(NTH), 0, stream,
                     x, Wt, out);
}

// Round 12
// 172.314 us; speedup vs baseline: 1.0856x; 1.0853x over previous
//
#include <hip/hip_runtime.h>
#include <cstddef>
#include <cstdint>

// DigitCaps dynamic routing — round 12: i-split + packed tail + (1024,8).
// Completes the r9/r10 matrix: r9 proved (1024,8) gives 2 blocks/CU (occ 72%)
// but its f32 tail spilled at the 64-VGPR budget; r10 proved the packed tail
// needs only 36 VGPR but without the attribute co-residency didn't happen
// (occ 43%). r11 proved occupancy alone is useless if W L2 traffic doubles.
// This round: identical to r10 EXCEPT sweep __launch_bounds__(1024) ->
// (1024, 8). W traffic stays 2.26 GB (each block sweeps half of W).
//   wprep -> sweep<0> -> combine<0> -> sweep<1> -> combine<1> -> sweep<2> -> combine<2>
// B=512, O=10, I=1152, OW=16, S=8, ITER=3.

typedef _Float16 h2 __attribute__((ext_vector_type(2)));
typedef __fp16 fp16v2 __attribute__((ext_vector_type(2)));  // cvt_pkrtz ret type

constexpr int O_ = 10, I_ = 1152, W_ = 16, S_ = 8;
constexpr int BQ = 2;               // batch items per block
constexpr int NTH = 1024, NWV = 16;
constexpr int IH = I_ / 2;          // 576: i per block (half range)
constexpr int SLOTS = NWV * 4;      // 64 concurrent i (16 lanes per i)
constexpr int KSEQ = IH / SLOTS;    // 9 sequential i per lane per sweep
constexpr int WROW = O_ * W_ * S_;  // 1280 halves per i in transposed W
constexpr int NBP = 256;            // batch pairs
constexpr int OW = O_ * W_;         // 160

union U32H2 { uint32_t u; h2 h; fp16v2 f; };
__device__ __forceinline__ h2 as_h2(uint32_t u) { U32H2 c; c.u = u; return c.h; }
__device__ __forceinline__ uint32_t as_u32(h2 h) { U32H2 c; c.h = h; return c.u; }
__device__ __forceinline__ h2 cvt_pk(float a, float b) {
  U32H2 c; c.f = __builtin_amdgcn_cvt_pkrtz(a, b); return c.h;
}

// W prep: fp32 [o][i][w][s] -> f16 [i][o][w][s]  (2,949,120 B into d_ws)
constexpr int W4TOT = O_ * I_ * W_ * S_ / 4;  // 368640 float4s
__global__ __launch_bounds__(256) void wprep(const float4* __restrict__ Wg,
                                             uint2* __restrict__ Wt) {
  int idx = blockIdx.x * 256 + threadIdx.x;
  if (idx >= W4TOT) return;
  int w2 = idx & 31;
  int oi = idx >> 5;        // o*I_ + i
  int o = oi / I_;
  int i = oi - o * I_;
  float4 v = Wg[idx];
  uint2 pk;
  pk.x = as_u32(cvt_pk(v.x, v.y));
  pk.y = as_u32(cvt_pk(v.z, v.w));
  Wt[(i * O_ + o) * 32 + w2] = pk;
}

__device__ __forceinline__ float dot8(const uint4& wv, const uint32_t* xr) {
  return __builtin_amdgcn_fdot2(as_h2(wv.x), as_h2(xr[0]),
          __builtin_amdgcn_fdot2(as_h2(wv.y), as_h2(xr[1]),
           __builtin_amdgcn_fdot2(as_h2(wv.z), as_h2(xr[2]),
            __builtin_amdgcn_fdot2(as_h2(wv.w), as_h2(xr[3]),
                                   0.f, false), false), false), false);
}

// Sweep: 512 blocks; block = (batch-pair bp, i-half h). Computes the partial
// s over its 576 i's and writes P[(bp*2+h)][bb][r]. PASS>0 reads Vcur.
// (1024, 8): request 8 waves/EU = 2 co-resident 1024-thread blocks per CU.
template <int PASS>
__global__ __launch_bounds__(NTH, 8) void sweep(
    const float* __restrict__ xg, const _Float16* __restrict__ Wt,
    const float* __restrict__ Vcur, float* __restrict__ P) {
  __shared__ _Float16 xl[BQ * IH * S_];      // 18,432 B
  __shared__ float s_buf[NWV][BQ][O_][W_];   // 20,480 B

  const int tid = threadIdx.x, blk = blockIdx.x;
  const int bp = blk >> 1, h = blk & 1, b0 = bp * BQ;
  const int wave = tid >> 6, lane = tid & 63;
  const int wg = lane & 15;     // w column 0..15
  const int isub = lane >> 4;   // 0..3
  const int ib = wave * 4 + isub;  // local i-slot; il = ib + 64*k

  // ---- stage this block's x slice -> f16 LDS ----
  {
    const float4* xb = (const float4*)xg;
    uint2* xw = (uint2*)xl;
#pragma unroll
    for (int j = 0; j < 3; ++j) {
      int f = j * NTH + tid;                 // 2304 float4s total
      if (f < BQ * IH * S_ / 4) {
        int b = f / (IH * S_ / 4);           // 0..1
        int rem = f - b * (IH * S_ / 4);
        float4 v = xb[(size_t)(b0 + b) * (I_ * S_ / 4) + h * (IH * S_ / 4) + rem];
        uint2 pk;
        pk.x = as_u32(cvt_pk(v.x, v.y));
        pk.y = as_u32(cvt_pk(v.z, v.w));
        xw[f] = pk;
      }
    }
  }
  __syncthreads();

  if (PASS == 0) {
    float S[BQ][O_];
#pragma unroll
    for (int b = 0; b < BQ; ++b)
#pragma unroll
      for (int o = 0; o < O_; ++o) S[b][o] = 0.f;

#pragma unroll 2
    for (int k = 0; k < KSEQ; ++k) {
      const int il = ib + SLOTS * k;
      const int gi = h * IH + il;
      uint32_t xr[BQ][4];
#pragma unroll
      for (int b = 0; b < BQ; ++b) {
        uint4 t = *(const uint4*)&xl[(b * IH + il) * S_];
        xr[b][0] = t.x; xr[b][1] = t.y; xr[b][2] = t.z; xr[b][3] = t.w;
      }
      const _Float16* wi = Wt + (size_t)gi * WROW + wg * S_;
#pragma unroll
      for (int o = 0; o < O_; ++o) {
        uint4 wv = *(const uint4*)(wi + o * (W_ * S_));
#pragma unroll
        for (int b = 0; b < BQ; ++b) S[b][o] += dot8(wv, xr[b]);
      }
    }
#pragma unroll
    for (int b = 0; b < BQ; ++b)
#pragma unroll
      for (int o = 0; o < O_; ++o) {
        float s = S[b][o];
        s += __shfl_xor(s, 16);
        s += __shfl_xor(s, 32);
        S[b][o] = s;
      }
    if (isub == 0) {
#pragma unroll
      for (int b = 0; b < BQ; ++b)
#pragma unroll
        for (int o = 0; o < O_; ++o) s_buf[wave][b][o][wg] = S[b][o];
    }
  } else {
    // packed batch-pair routing; fully-packed softmax tail (36 VGPR in r10)
    h2 vrpk[O_];
#pragma unroll
    for (int o = 0; o < O_; ++o)
      vrpk[o] = cvt_pk(Vcur[(size_t)(b0 + 0) * OW + o * W_ + wg],
                       Vcur[(size_t)(b0 + 1) * OW + o * W_ + wg]);
    h2 Spk[O_];
#pragma unroll
    for (int o = 0; o < O_; ++o) Spk[o] = h2{(_Float16)0, (_Float16)0};

#pragma unroll 2
    for (int k = 0; k < KSEQ; ++k) {
      const int il = ib + SLOTS * k;
      const int gi = h * IH + il;
      uint32_t xr[BQ][4];
#pragma unroll
      for (int b = 0; b < BQ; ++b) {
        uint4 t = *(const uint4*)&xl[(b * IH + il) * S_];
        xr[b][0] = t.x; xr[b][1] = t.y; xr[b][2] = t.z; xr[b][3] = t.w;
      }
      const _Float16* wi = Wt + (size_t)gi * WROW + wg * S_;
      h2 upk[O_], ppk[O_];
#pragma unroll
      for (int o = 0; o < O_; ++o) {
        uint4 wv = *(const uint4*)(wi + o * (W_ * S_));
        float u0 = dot8(wv, xr[0]);
        float u1 = dot8(wv, xr[1]);
        upk[o] = cvt_pk(u0, u1);
        ppk[o] = upk[o] * vrpk[o];
      }
#pragma unroll
      for (int o = 0; o < O_; ++o) {
#pragma unroll
        for (int d = 1; d <= 8; d <<= 1)
          ppk[o] = ppk[o] + as_h2((uint32_t)__shfl_xor((int)as_u32(ppk[o]), d));
      }
      // softmax over o — packed end-to-end
      h2 es_pk = h2{(_Float16)0, (_Float16)0};
#pragma unroll
      for (int o = 0; o < O_; ++o) {
        h2 e = cvt_pk(__expf((float)ppk[o][0]), __expf((float)ppk[o][1]));
        ppk[o] = e;
        es_pk = es_pk + e;
      }
      const h2 inv_pk = cvt_pk(1.0f / (float)es_pk[0], 1.0f / (float)es_pk[1]);
#pragma unroll
      for (int o = 0; o < O_; ++o)
        Spk[o] = Spk[o] + (ppk[o] * inv_pk) * upk[o];
    }
#pragma unroll
    for (int o = 0; o < O_; ++o) {
      Spk[o] = Spk[o] + as_h2((uint32_t)__shfl_xor((int)as_u32(Spk[o]), 16));
      Spk[o] = Spk[o] + as_h2((uint32_t)__shfl_xor((int)as_u32(Spk[o]), 32));
    }
    if (isub == 0) {
#pragma unroll
      for (int o = 0; o < O_; ++o) {
        s_buf[wave][0][o][wg] = (float)Spk[o][0];
        s_buf[wave][1][o][wg] = (float)Spk[o][1];
      }
    }
  }
  __syncthreads();

  // block partial (sum over 16 waves) -> global P
  if (tid < BQ * OW) {
    const int bb = tid / OW;
    const int r = tid % OW;
    float s = 0.f;
#pragma unroll
    for (int wv = 0; wv < NWV; ++wv) s += s_buf[wv][bb][r >> 4][r & 15];
    P[((size_t)(bp * 2 + h) * BQ + bb) * OW + r] = s;
  }
}

// Combine: 256 blocks x 320 threads. Sum the two i-half partials, squash,
// update Vcur / V1 / out.
template <int PASS>
__global__ __launch_bounds__(320) void combine(
    const float* __restrict__ P, float* __restrict__ Vcur,
    float* __restrict__ V1, float* __restrict__ out) {
  const int bp = blockIdx.x, tid = threadIdx.x;   // tid < 320
  const int bb = tid / OW, r = tid % OW;
  float s = P[((size_t)(bp * 2 + 0) * BQ + bb) * OW + r]
          + P[((size_t)(bp * 2 + 1) * BQ + bb) * OW + r];
  if (PASS == 0) s *= 0.1f;
  float n2 = s * s;
  n2 += __shfl_xor(n2, 1);
  n2 += __shfl_xor(n2, 2);
  n2 += __shfl_xor(n2, 4);
  n2 += __shfl_xor(n2, 8);
  const float v = s * sqrtf(n2) / (1.0f + n2);  // == (n2/(1+n2))*s/sqrt(n2)
  const size_t gi = (size_t)(bp * BQ + bb) * OW + r;
  if (PASS == 0)      { Vcur[gi] = v; V1[gi] = v; }
  else if (PASS == 1) { Vcur[gi] = V1[gi] + v; }   // v1+v2 for pass 2
  else                { out[gi] = v; }
}

extern "C" void kernel_launch(void* const* d_in, const int* in_sizes, int n_in,
                              void* d_out, int out_size, void* d_ws, size_t ws_size,
                              hipStream_t stream) {
  const float* x = (const float*)d_in[0];   // [512, 1152, 8]
  const float* W = (const float*)d_in[1];   // [1, 10, 1152, 16, 8]
  float* out = (float*)d_out;               // [512, 10, 16]

  // ws layout: Wt (2,949,120 B) | P (655,360 B) | Vcur (327,680 B) | V1 (327,680 B)
  _Float16* Wt = (_Float16*)d_ws;
  float* P  = (float*)((char*)d_ws + 2949120);
  float* Vc = (float*)((char*)d_ws + 2949120 + 655360);
  float* V1 = (float*)((char*)d_ws + 2949120 + 655360 + 327680);

  hipLaunchKernelGGL(wprep, dim3((W4TOT + 255) / 256), dim3(256), 0, stream,
                     (const float4*)W, (uint2*)Wt);
  sweep<0><<<dim3(2 * NBP), dim3(NTH), 0, stream>>>(x, Wt, Vc, P);
  combine<0><<<dim3(NBP), dim3(320), 0, stream>>>(P, Vc, V1, out);
  sweep<1><<<dim3(2 * NBP), dim3(NTH), 0, stream>>>(x, Wt, Vc, P);
  combine<1><<<dim3(NBP), dim3(320), 0, stream>>>(P, Vc, V1, out);
  sweep<2><<<dim3(2 * NBP), dim3(NTH), 0, stream>>>(x, Wt, Vc, P);
  combine<2><<<dim3(NBP), dim3(320), 0, stream>>>(P, Vc, V1, out);
}

// Round 13
// 166.329 us; speedup vs baseline: 1.1247x; 1.0360x over previous
//
#include <hip/hip_runtime.h>
#include <cstddef>
#include <cstdint>

// DigitCaps dynamic routing — round 13: 256-thread blocks, 8 blocks/CU.
// r9-r12 matrix: co-residency needs the waves-per-eu hint, but with
// 1024-thread blocks the hint squeezes to 32 VGPR and spills the ~50-reg
// routing tail (r12: 8.8 MB scratch, 70 us sweeps). Small blocks resolve it:
// (256,8) = 8 blocks/CU = 32 waves/CU at a 64-reg budget the compiler
// honors (tail needs ~36). i-split x8 (IH=144), grid = 256 bp x 8 = 2048
// blocks = exactly 8/CU; W traffic per sweep unchanged (755 MB).
//   wprep -> sweep<0> -> combine<0> -> sweep<1> -> combine<1> -> sweep<2> -> combine<2>
// B=512, O=10, I=1152, OW=16, S=8, ITER=3.

typedef _Float16 h2 __attribute__((ext_vector_type(2)));
typedef __fp16 fp16v2 __attribute__((ext_vector_type(2)));  // cvt_pkrtz ret type

constexpr int O_ = 10, I_ = 1152, W_ = 16, S_ = 8;
constexpr int BQ = 2;               // batch items per block
constexpr int NTH = 256, NWV = 4;   // 4 waves per block
constexpr int NSPL = 8;             // i-split factor
constexpr int IH = I_ / NSPL;       // 144: i per block
constexpr int SLOTS = NWV * 4;      // 16 concurrent i (16 lanes per i)
constexpr int KSEQ = IH / SLOTS;    // 9 sequential i per lane per sweep
constexpr int WROW = O_ * W_ * S_;  // 1280 halves per i in transposed W
constexpr int NBP = 256;            // batch pairs
constexpr int OW = O_ * W_;         // 160

union U32H2 { uint32_t u; h2 h; fp16v2 f; };
__device__ __forceinline__ h2 as_h2(uint32_t u) { U32H2 c; c.u = u; return c.h; }
__device__ __forceinline__ uint32_t as_u32(h2 h) { U32H2 c; c.h = h; return c.u; }
__device__ __forceinline__ h2 cvt_pk(float a, float b) {
  U32H2 c; c.f = __builtin_amdgcn_cvt_pkrtz(a, b); return c.h;
}

// W prep: fp32 [o][i][w][s] -> f16 [i][o][w][s]  (2,949,120 B into d_ws)
constexpr int W4TOT = O_ * I_ * W_ * S_ / 4;  // 368640 float4s
__global__ __launch_bounds__(256) void wprep(const float4* __restrict__ Wg,
                                             uint2* __restrict__ Wt) {
  int idx = blockIdx.x * 256 + threadIdx.x;
  if (idx >= W4TOT) return;
  int w2 = idx & 31;
  int oi = idx >> 5;        // o*I_ + i
  int o = oi / I_;
  int i = oi - o * I_;
  float4 v = Wg[idx];
  uint2 pk;
  pk.x = as_u32(cvt_pk(v.x, v.y));
  pk.y = as_u32(cvt_pk(v.z, v.w));
  Wt[(i * O_ + o) * 32 + w2] = pk;
}

__device__ __forceinline__ float dot8(const uint4& wv, const uint32_t* xr) {
  return __builtin_amdgcn_fdot2(as_h2(wv.x), as_h2(xr[0]),
          __builtin_amdgcn_fdot2(as_h2(wv.y), as_h2(xr[1]),
           __builtin_amdgcn_fdot2(as_h2(wv.z), as_h2(xr[2]),
            __builtin_amdgcn_fdot2(as_h2(wv.w), as_h2(xr[3]),
                                   0.f, false), false), false), false);
}

// Sweep: 2048 blocks; block = (batch-pair bp, i-octant h). Partial s over its
// 144 i's -> P[(bp*8+h)][bb][r]. PASS>0 reads Vcur.
// (256, 8): 8 waves/EU => 8 blocks/CU, 64-VGPR budget.
template <int PASS>
__global__ __launch_bounds__(NTH, 8) void sweep(
    const float* __restrict__ xg, const _Float16* __restrict__ Wt,
    const float* __restrict__ Vcur, float* __restrict__ P) {
  __shared__ _Float16 xl[BQ * IH * S_];      // 4,608 B
  __shared__ float s_buf[NWV][BQ][O_][W_];   // 5,120 B

  const int tid = threadIdx.x, blk = blockIdx.x;
  const int bp = blk >> 3, h = blk & 7, b0 = bp * BQ;
  const int wave = tid >> 6, lane = tid & 63;
  const int wg = lane & 15;     // w column 0..15
  const int isub = lane >> 4;   // 0..3
  const int ib = wave * 4 + isub;  // local i-slot; il = ib + 16*k

  // ---- stage this block's x slice -> f16 LDS ----
  {
    const float4* xb = (const float4*)xg;
    uint2* xw = (uint2*)xl;
#pragma unroll
    for (int j = 0; j < 3; ++j) {
      int f = j * NTH + tid;                 // 576 float4s total
      if (f < BQ * IH * S_ / 4) {
        int b = f / (IH * S_ / 4);           // 0..1
        int rem = f - b * (IH * S_ / 4);
        float4 v = xb[(size_t)(b0 + b) * (I_ * S_ / 4) + h * (IH * S_ / 4) + rem];
        uint2 pk;
        pk.x = as_u32(cvt_pk(v.x, v.y));
        pk.y = as_u32(cvt_pk(v.z, v.w));
        xw[f] = pk;
      }
    }
  }
  __syncthreads();

  if (PASS == 0) {
    float S[BQ][O_];
#pragma unroll
    for (int b = 0; b < BQ; ++b)
#pragma unroll
      for (int o = 0; o < O_; ++o) S[b][o] = 0.f;

#pragma unroll 2
    for (int k = 0; k < KSEQ; ++k) {
      const int il = ib + SLOTS * k;
      const int gi = h * IH + il;
      uint32_t xr[BQ][4];
#pragma unroll
      for (int b = 0; b < BQ; ++b) {
        uint4 t = *(const uint4*)&xl[(b * IH + il) * S_];
        xr[b][0] = t.x; xr[b][1] = t.y; xr[b][2] = t.z; xr[b][3] = t.w;
      }
      const _Float16* wi = Wt + (size_t)gi * WROW + wg * S_;
#pragma unroll
      for (int o = 0; o < O_; ++o) {
        uint4 wv = *(const uint4*)(wi + o * (W_ * S_));
#pragma unroll
        for (int b = 0; b < BQ; ++b) S[b][o] += dot8(wv, xr[b]);
      }
    }
#pragma unroll
    for (int b = 0; b < BQ; ++b)
#pragma unroll
      for (int o = 0; o < O_; ++o) {
        float s = S[b][o];
        s += __shfl_xor(s, 16);
        s += __shfl_xor(s, 32);
        S[b][o] = s;
      }
    if (isub == 0) {
#pragma unroll
      for (int b = 0; b < BQ; ++b)
#pragma unroll
        for (int o = 0; o < O_; ++o) s_buf[wave][b][o][wg] = S[b][o];
    }
  } else {
    // packed batch-pair routing; fully-packed softmax tail (~36 VGPR natural)
    h2 vrpk[O_];
#pragma unroll
    for (int o = 0; o < O_; ++o)
      vrpk[o] = cvt_pk(Vcur[(size_t)(b0 + 0) * OW + o * W_ + wg],
                       Vcur[(size_t)(b0 + 1) * OW + o * W_ + wg]);
    h2 Spk[O_];
#pragma unroll
    for (int o = 0; o < O_; ++o) Spk[o] = h2{(_Float16)0, (_Float16)0};

#pragma unroll 2
    for (int k = 0; k < KSEQ; ++k) {
      const int il = ib + SLOTS * k;
      const int gi = h * IH + il;
      uint32_t xr[BQ][4];
#pragma unroll
      for (int b = 0; b < BQ; ++b) {
        uint4 t = *(const uint4*)&xl[(b * IH + il) * S_];
        xr[b][0] = t.x; xr[b][1] = t.y; xr[b][2] = t.z; xr[b][3] = t.w;
      }
      const _Float16* wi = Wt + (size_t)gi * WROW + wg * S_;
      h2 upk[O_], ppk[O_];
#pragma unroll
      for (int o = 0; o < O_; ++o) {
        uint4 wv = *(const uint4*)(wi + o * (W_ * S_));
        float u0 = dot8(wv, xr[0]);
        float u1 = dot8(wv, xr[1]);
        upk[o] = cvt_pk(u0, u1);
        ppk[o] = upk[o] * vrpk[o];
      }
#pragma unroll
      for (int o = 0; o < O_; ++o) {
#pragma unroll
        for (int d = 1; d <= 8; d <<= 1)
          ppk[o] = ppk[o] + as_h2((uint32_t)__shfl_xor((int)as_u32(ppk[o]), d));
      }
      // softmax over o — packed end-to-end
      h2 es_pk = h2{(_Float16)0, (_Float16)0};
#pragma unroll
      for (int o = 0; o < O_; ++o) {
        h2 e = cvt_pk(__expf((float)ppk[o][0]), __expf((float)ppk[o][1]));
        ppk[o] = e;
        es_pk = es_pk + e;
      }
      const h2 inv_pk = cvt_pk(1.0f / (float)es_pk[0], 1.0f / (float)es_pk[1]);
#pragma unroll
      for (int o = 0; o < O_; ++o)
        Spk[o] = Spk[o] + (ppk[o] * inv_pk) * upk[o];
    }
#pragma unroll
    for (int o = 0; o < O_; ++o) {
      Spk[o] = Spk[o] + as_h2((uint32_t)__shfl_xor((int)as_u32(Spk[o]), 16));
      Spk[o] = Spk[o] + as_h2((uint32_t)__shfl_xor((int)as_u32(Spk[o]), 32));
    }
    if (isub == 0) {
#pragma unroll
      for (int o = 0; o < O_; ++o) {
        s_buf[wave][0][o][wg] = (float)Spk[o][0];
        s_buf[wave][1][o][wg] = (float)Spk[o][1];
      }
    }
  }
  __syncthreads();

  // block partial (sum over 4 waves) -> global P
  if (tid < BQ * OW) {  // 320 of 256... NTH=256 < 320: two rows per thread
  }
  // NTH=256 < BQ*OW=320: cover 320 outputs with 256 threads (некоторые do 2)
  for (int t = tid; t < BQ * OW; t += NTH) {
    const int bb = t / OW;
    const int r = t % OW;
    float s = 0.f;
#pragma unroll
    for (int wv = 0; wv < NWV; ++wv) s += s_buf[wv][bb][r >> 4][r & 15];
    P[((size_t)(bp * NSPL + h) * BQ + bb) * OW + r] = s;
  }
}

// Combine: 256 blocks x 320 threads. Sum the 8 i-octant partials, squash,
// update Vcur / V1 / out.
template <int PASS>
__global__ __launch_bounds__(320) void combine(
    const float* __restrict__ P, float* __restrict__ Vcur,
    float* __restrict__ V1, float* __restrict__ out) {
  const int bp = blockIdx.x, tid = threadIdx.x;   // tid < 320
  const int bb = tid / OW, r = tid % OW;
  float s = 0.f;
#pragma unroll
  for (int h = 0; h < NSPL; ++h)
    s += P[((size_t)(bp * NSPL + h) * BQ + bb) * OW + r];
  if (PASS == 0) s *= 0.1f;
  float n2 = s * s;
  n2 += __shfl_xor(n2, 1);
  n2 += __shfl_xor(n2, 2);
  n2 += __shfl_xor(n2, 4);
  n2 += __shfl_xor(n2, 8);
  const float v = s * sqrtf(n2) / (1.0f + n2);  // == (n2/(1+n2))*s/sqrt(n2)
  const size_t gi = (size_t)(bp * BQ + bb) * OW + r;
  if (PASS == 0)      { Vcur[gi] = v; V1[gi] = v; }
  else if (PASS == 1) { Vcur[gi] = V1[gi] + v; }   // v1+v2 for pass 2
  else                { out[gi] = v; }
}

extern "C" void kernel_launch(void* const* d_in, const int* in_sizes, int n_in,
                              void* d_out, int out_size, void* d_ws, size_t ws_size,
                              hipStream_t stream) {
  const float* x = (const float*)d_in[0];   // [512, 1152, 8]
  const float* W = (const float*)d_in[1];   // [1, 10, 1152, 16, 8]
  float* out = (float*)d_out;               // [512, 10, 16]

  // ws layout: Wt (2,949,120 B) | P (2048*2*160*4 = 2,621,440 B) |
  //            Vcur (327,680 B) | V1 (327,680 B)
  _Float16* Wt = (_Float16*)d_ws;
  float* P  = (float*)((char*)d_ws + 2949120);
  float* Vc = (float*)((char*)d_ws + 2949120 + 2621440);
  float* V1 = (float*)((char*)d_ws + 2949120 + 2621440 + 327680);

  hipLaunchKernelGGL(wprep, dim3((W4TOT + 255) / 256), dim3(256), 0, stream,
                     (const float4*)W, (uint2*)Wt);
  sweep<0><<<dim3(NSPL * NBP), dim3(NTH), 0, stream>>>(x, Wt, Vc, P);
  combine<0><<<dim3(NBP), dim3(320), 0, stream>>>(P, Vc, V1, out);
  sweep<1><<<dim3(NSPL * NBP), dim3(NTH), 0, stream>>>(x, Wt, Vc, P);
  combine<1><<<dim3(NBP), dim3(320), 0, stream>>>(P, Vc, V1, out);
  sweep<2><<<dim3(NSPL * NBP), dim3(NTH), 0, stream>>>(x, Wt, Vc, P);
  combine<2><<<dim3(NBP), dim3(320), 0, stream>>>(P, Vc, V1, out);
}